// Round 11
// baseline (69.446 us; speedup 1.0000x reference)
//
#include <hip/hip_runtime.h>

constexpr int NENV = 4096;
constexpr int GD   = 64;
constexpr int RD3  = 192;

typedef __attribute__((ext_vector_type(8))) short s16x8;
typedef __attribute__((ext_vector_type(4))) short s16x4;
typedef __attribute__((ext_vector_type(4))) float f32x4;

__device__ __forceinline__ unsigned short f2bf(float f) {
    unsigned u = __float_as_uint(f);
    u += 0x7FFFu + ((u >> 16) & 1u);
    return (unsigned short)(u >> 16);
}
__device__ __forceinline__ float bf2f(unsigned short u) {
    return __uint_as_float((unsigned)u << 16);
}
__device__ __forceinline__ float sigm(float v) { return 1.f / (1.f + __expf(-v)); }

#define MFMA16(A, B, C) __builtin_amdgcn_mfma_f32_16x16x32_bf16(A, B, C, 0, 0, 0)

// ---- K0: blocks 0..95 cvt W_ih/W_hh -> bf16; block 96 folds Wc^T (bf16) + bc ----
__global__ __launch_bounds__(256) void prep_kernel(
    const float* __restrict__ W_pre, const float* __restrict__ b_pre,
    const float* __restrict__ W_gcn,
    const float* __restrict__ W_ih,  const float* __restrict__ W_hh,
    short* __restrict__ WcTB, float* __restrict__ bcw,
    short* __restrict__ WihB, short* __restrict__ WhhB)
{
    int b = blockIdx.x, t = threadIdx.x;
    if (b == 96) {
        for (int o = t; o < 32 * GD; o += 256) {
            int k = o >> 6, d = o & 63;
            float s = 0.f;
            for (int m = 0; m < GD; ++m) s += W_pre[k * GD + m] * W_gcn[m * GD + d];
            WcTB[d * 32 + k] = (short)f2bf(s);
        }
        if (t < GD) {
            float s = 0.f;
            for (int m = 0; m < GD; ++m) s += b_pre[m] * W_gcn[m * GD + t];
            bcw[t] = s;
        }
    } else {
        int i = b * 256 + t;
        if (i < RD3 * GD) WihB[i] = (short)f2bf(W_ih[i]);
        else              WhhB[i - RD3 * GD] = (short)f2bf(W_hh[i - RD3 * GD]);
    }
}

// ==== K1: GCN, persistent. 512 blocks (2/CU, single generation), wave = env, ====
// 2 envs per wave with next-env loads issued under current-env compute. 0 barriers.
__global__ __launch_bounds__(256) void gcn_kernel(
    const float* __restrict__ x,      // [4096][32][32]
    const void*  __restrict__ edge,   // [4096][2][256] int32 or int64
    const float* __restrict__ bcw,    // [64]
    const float* __restrict__ b_gcn,  // [64]
    const short* __restrict__ WcTB,   // [64][32] bf16
    float* __restrict__ hid)          // [N] env slots of 8KB; low 4KB = swz agg
{
    __shared__ __align__(16) char smem[39936];

    const int t   = threadIdx.x;
    const int w   = t >> 6;
    const int l   = t & 63;
    const int col = l & 15, lg = l >> 4;
    const int gwave = blockIdx.x * 4 + w;        // 0..2047

    char*  eb    = smem + w * 9984;
    float* cnts  = (float*)eb;
    short* yB    = (short*)eb;
    short* xT    = (short*)(eb + 4608);
    short* Ah    = (short*)(eb + 7168);
    char*  aggB  = eb + 4608;                    // overlays dead xT/Ah after P5
    float* sdinv = (float*)(eb + 9728);
    float* srsum = (float*)(eb + 9856);

    // dtype probe once (first 2KB)
    const int4* pg = (const int4*)edge;
    int4 pa = pg[l], pb = pg[l + 64];
    const bool is32 = (__any((pa.y | pa.w | pb.y | pb.w) != 0) != 0);

    auto loadX = [&](int env, f32x4* out) {
        #pragma unroll
        for (int i = 0; i < 4; ++i)
            out[i] = ((const f32x4*)(x + (size_t)env * 1024))[l + i * 64];
    };
    auto loadE = [&](int env, int* rr, int* cc) {
        if (is32) {
            const int4* e4 = (const int4*)((const char*)edge + (size_t)env * 2048);
            int4 r4 = e4[l], c4 = e4[64 + l];
            rr[0] = r4.x; rr[1] = r4.y; rr[2] = r4.z; rr[3] = r4.w;
            cc[0] = c4.x; cc[1] = c4.y; cc[2] = c4.z; cc[3] = c4.w;
        } else {
            const int4* e4 = (const int4*)((const char*)edge + (size_t)env * 4096);
            int4 ra = e4[2 * l], rb = e4[2 * l + 1];
            int4 ca = e4[128 + 2 * l], cb = e4[128 + 2 * l + 1];
            rr[0] = ra.x; rr[1] = ra.z; rr[2] = rb.x; rr[3] = rb.z;
            cc[0] = ca.x; cc[1] = ca.z; cc[2] = cb.x; cc[3] = cb.z;
        }
    };

    f32x4 xq[4], xq2[4];
    int rr_[4], cc_[4], rr2[4], cc2[4];
    loadX(gwave, xq);
    loadE(gwave, rr_, cc_);

    auto doEnv = [&](int env, const f32x4* xqv, const int* rr, const int* cc,
                     bool prefetch) {
        // ---- P1: zero counts, stage xT ----
        #pragma unroll
        for (int i = 0; i < 5; ++i) {
            int o = l + i * 64;
            if (o < 288) ((f32x4*)cnts)[o] = (f32x4){0.f, 0.f, 0.f, 0.f};
        }
        #pragma unroll
        for (int i = 0; i < 4; ++i) {
            int idx4 = l + i * 64;
            int n = idx4 >> 3, q = idx4 & 7;
            #pragma unroll
            for (int j = 0; j < 4; ++j) xT[(q * 4 + j) * 40 + n] = (short)f2bf(xqv[i][j]);
        }
        // ---- P2: adjacency counts ----
        #pragma unroll
        for (int j = 0; j < 4; ++j) atomicAdd(cnts + cc[j] * 36 + rr[j], 1.0f);

        // ---- prefetch next env (loads fly under P3..P7) ----
        if (prefetch) {
            loadX(gwave + 2048, xq2);
            loadE(gwave + 2048, rr2, cc2);
        }

        // ---- P3: degree + dinv ----
        const int c_  = l >> 1;
        const int r0_ = (l & 1) * 16;
        f32x4 cv[4];
        float s16s = 0.f;
        #pragma unroll
        for (int q = 0; q < 4; ++q) {
            cv[q] = *(const f32x4*)(cnts + c_ * 36 + r0_ + q * 4);
            s16s += cv[q][0] + cv[q][1] + cv[q][2] + cv[q][3];
        }
        float degs = s16s + __shfl_xor(s16s, 1, 64);
        float dc = rsqrtf(1.0f + degs);
        if (!(l & 1)) sdinv[c_] = dc;

        // ---- P4: normalize -> Ah bf16, rowsum ----
        {
            f32x4 dv[4];
            #pragma unroll
            for (int q = 0; q < 4; ++q) dv[q] = *(const f32x4*)(sdinv + r0_ + q * 4);
            float dot = 0.f;
            s16x8 o0, o1;
            #pragma unroll
            for (int k = 0; k < 16; ++k) {
                float u = cv[k >> 2][k & 3] * dv[k >> 2][k & 3];
                dot += u;
                float v = u * dc;
                if (r0_ + k == c_) v += dc * dc;
                if (k < 8) o0[k] = (short)f2bf(v); else o1[k - 8] = (short)f2bf(v);
            }
            dot += __shfl_xor(dot, 1, 64);
            if (!(l & 1)) srsum[c_] = dc * dot + dc * dc;
            *(s16x8*)(Ah + c_ * 40 + r0_)     = o0;
            *(s16x8*)(Ah + c_ * 40 + r0_ + 8) = o1;
        }

        // ---- P5: yT = xT @ AhatT (4 MFMA) ----
        {
            s16x8 Ax0 = *(const s16x8*)(xT + col * 40 + lg * 8);
            s16x8 Ax1 = *(const s16x8*)(xT + (16 + col) * 40 + lg * 8);
            s16x8 Af0 = *(const s16x8*)(Ah + col * 40 + lg * 8);
            s16x8 Af1 = *(const s16x8*)(Ah + (16 + col) * 40 + lg * 8);
            f32x4 y00 = {}, y01 = {}, y10 = {}, y11 = {};
            y00 = MFMA16(Ax0, Af0, y00);
            y01 = MFMA16(Ax0, Af1, y01);
            y10 = MFMA16(Ax1, Af0, y10);
            y11 = MFMA16(Ax1, Af1, y11);
            #pragma unroll
            for (int f = 0; f < 2; ++f)
                #pragma unroll
                for (int d = 0; d < 2; ++d) {
                    f32x4 a = (f == 0) ? (d == 0 ? y00 : y01) : (d == 0 ? y10 : y11);
                    s16x4 pk;
                    pk[0] = (short)f2bf(a[0]); pk[1] = (short)f2bf(a[1]);
                    pk[2] = (short)f2bf(a[2]); pk[3] = (short)f2bf(a[3]);
                    *(s16x4*)(yB + (d * 16 + col) * 40 + f * 16 + lg * 4) = pk;
                }
        }

        // ---- P6: aggT = WcT @ yT (8 MFMA) -> aggB swz ----
        {
            s16x8 Aw[4];
            #pragma unroll
            for (int a = 0; a < 4; ++a)
                Aw[a] = *(const s16x8*)(WcTB + (a * 16 + col) * 32 + lg * 8);
            s16x8 By0 = *(const s16x8*)(yB + col * 40 + lg * 8);
            s16x8 By1 = *(const s16x8*)(yB + (16 + col) * 40 + lg * 8);
            float rs0 = srsum[col], rs1 = srsum[16 + col];
            #pragma unroll
            for (int a = 0; a < 4; ++a) {
                f32x4 g0 = {}, g1 = {};
                g0 = MFMA16(Aw[a], By0, g0);
                g1 = MFMA16(Aw[a], By1, g1);
                f32x4 bc4 = *(const f32x4*)(bcw + a * 16 + lg * 4);
                f32x4 bg4 = *(const f32x4*)(b_gcn + a * 16 + lg * 4);
                #pragma unroll
                for (int n = 0; n < 2; ++n) {
                    f32x4 g = n ? g1 : g0;
                    float rs = n ? rs1 : rs0;
                    int node = n * 16 + col;
                    s16x4 pk;
                    #pragma unroll
                    for (int r = 0; r < 4; ++r)
                        pk[r] = (short)f2bf(g[r] + rs * bc4[r] + bg4[r]);
                    *(s16x4*)(aggB + node * 128 + ((a * 32 + lg * 8) ^ ((node & 7) << 4))) = pk;
                }
            }
        }

        // ---- P7: LINEAR flush of pre-swizzled agg bytes ----
        {
            char* agout = (char*)hid + (size_t)env * 8192;
            #pragma unroll
            for (int i = 0; i < 4; ++i) {
                int idx = l + i * 64;
                s16x8 v = *(const s16x8*)(aggB + idx * 16);
                *(s16x8*)(agout + idx * 16) = v;
            }
        }
    };

    doEnv(gwave,        xq,  rr_, cc_, true);
    doEnv(gwave + 2048, xq2, rr2, cc2, false);
}

// ==== K2: GRU + value head, persistent. 512 blocks (2/CU, single generation). ====
// Weights staged once; group1 loads issued into regs before group0 compute.
// LDS: [0,49152) W swz | per-env e at 49152+e*8192: [agg 4KB | h0 4KB] -> hnew.
__global__ __launch_bounds__(256) void gru_kernel(
    const float* __restrict__ h0f,    // [N][64] f32
    const short* __restrict__ WihB,   // [192][64] bf16 (ws)
    const short* __restrict__ WhhB,   // [192][64] bf16 (ws)
    const float* __restrict__ b_ih, const float* __restrict__ b_hh,
    const float* __restrict__ W_out,  // [2048]
    const float* __restrict__ b_out,
    float* __restrict__ value,        // [4096]
    float* __restrict__ hid)          // env slots of 8KB; low 4KB = swz agg (in)
{
    __shared__ __align__(16) char smem[81920];
    char* sw = smem;

    const int t = threadIdx.x, w = t >> 6, l = t & 63;
    const int col = l & 15, lg = l >> 4;

    // ---- stage W (48KB, swizzled) ----
    #pragma unroll
    for (int i = 0; i < 12; ++i) {
        int off = (t + i * 256) * 16;
        const char* src = (off < 24576) ? (const char*)WihB + off
                                        : (const char*)WhhB + (off - 24576);
        s16x8 v = *(const s16x8*)src;
        *(s16x8*)(sw + (off ^ (((off >> 7) & 7) << 4))) = v;
    }
    // ---- stage group0 (agg raw + h0 cvt/swz), coalesced ----
    {
        const char* aggsrc = (const char*)hid + (size_t)blockIdx.x * 32768;
        #pragma unroll
        for (int i = 0; i < 4; ++i) {
            int idx = t + i * 256, e = idx >> 8, q = idx & 255;
            s16x8 v = *(const s16x8*)(aggsrc + e * 8192 + q * 16);
            *(s16x8*)(smem + 49152 + e * 8192 + q * 16) = v;
        }
        const float* h0src = h0f + (size_t)blockIdx.x * 8192;
        #pragma unroll
        for (int i = 0; i < 8; ++i) {
            int idx = t + i * 256;
            f32x4 hv = *(const f32x4*)(h0src + idx * 4);
            s16x4 pk;
            pk[0] = (short)f2bf(hv[0]); pk[1] = (short)f2bf(hv[1]);
            pk[2] = (short)f2bf(hv[2]); pk[3] = (short)f2bf(hv[3]);
            int e = idx >> 9, off = (idx & 511) * 8;
            int row = off >> 7, rb = off & 127;
            *(s16x4*)(smem + 49152 + e * 8192 + 4096 + row * 128 +
                      (rb ^ ((row & 7) << 4))) = pk;
        }
    }
    __syncthreads();

    // ---- issue group1 global loads into registers (fly under group0 compute) ----
    s16x8 aggv[4];
    f32x4 h0v[8];
    {
        const char* aggsrc = (const char*)hid + ((size_t)blockIdx.x + 512) * 32768;
        #pragma unroll
        for (int i = 0; i < 4; ++i) {
            int idx = t + i * 256, e = idx >> 8, q = idx & 255;
            aggv[i] = *(const s16x8*)(aggsrc + e * 8192 + q * 16);
        }
        const float* h0src = h0f + ((size_t)blockIdx.x + 512) * 8192;
        #pragma unroll
        for (int i = 0; i < 8; ++i) h0v[i] = *(const f32x4*)(h0src + i * 256 * 4 + t * 4);
    }

    auto computeEnv = [&](int g) {
        const int env = blockIdx.x * 4 + w + g * 2048;
        char* eb  = smem + 49152 + w * 8192;
        char* agg = eb;
        char* h0b = eb + 4096;

        // preload ALL LDS-sourced fragments (before hnew overwrites region)
        s16x8 Ba[4], Hb[4];
        #pragma unroll
        for (int kt = 0; kt < 2; ++kt)
            #pragma unroll
            for (int nt = 0; nt < 2; ++nt) {
                int node = nt * 16 + col;
                int o = node * 128 + ((kt * 64 + lg * 16) ^ ((node & 7) << 4));
                Ba[kt * 2 + nt] = *(const s16x8*)(agg + o);
                Hb[kt * 2 + nt] = *(const s16x8*)(h0b + o);
            }
        s16x4 hbl[8];
        #pragma unroll
        for (int gd = 0; gd < 4; ++gd)
            #pragma unroll
            for (int nt = 0; nt < 2; ++nt) {
                int node = nt * 16 + col;
                hbl[gd * 2 + nt] = *(const s16x4*)(h0b + node * 128 +
                                     ((gd * 32 + lg * 8) ^ ((node & 7) << 4)));
            }

        auto WF = [&](int hh, int g3, int gd, int kt) -> s16x8 {
            int row = g3 * 64 + gd * 16 + col;
            int off = hh * 24576 + row * 128 + kt * 64 + lg * 16;
            return *(const s16x8*)(sw + (off ^ ((row & 7) << 4)));
        };

        #pragma unroll
        for (int gd = 0; gd < 4; ++gd) {
            const int db = gd * 16 + lg * 4;
            f32x4 br  = *(const f32x4*)(b_ih + db);
            f32x4 bz  = *(const f32x4*)(b_ih + 64 + db);
            f32x4 bin = *(const f32x4*)(b_ih + 128 + db);
            f32x4 bhn = *(const f32x4*)(b_hh + 128 + db);
            {
                f32x4 t1 = *(const f32x4*)(b_hh + db);
                f32x4 t2 = *(const f32x4*)(b_hh + 64 + db);
                br += t1; bz += t2;
            }

            f32x4 ar[2] = {}, az[2] = {}, ain[2] = {}, ahn[2] = {};
            __builtin_amdgcn_s_setprio(1);
            #pragma unroll
            for (int kt = 0; kt < 2; ++kt) {
                s16x8 Wri = WF(0, 0, gd, kt), Wrh = WF(1, 0, gd, kt);
                s16x8 Wzi = WF(0, 1, gd, kt), Wzh = WF(1, 1, gd, kt);
                s16x8 Wni = WF(0, 2, gd, kt), Wnh = WF(1, 2, gd, kt);
                #pragma unroll
                for (int nt = 0; nt < 2; ++nt) {
                    ar[nt]  = MFMA16(Wri, Ba[kt * 2 + nt], ar[nt]);
                    ar[nt]  = MFMA16(Wrh, Hb[kt * 2 + nt], ar[nt]);
                    az[nt]  = MFMA16(Wzi, Ba[kt * 2 + nt], az[nt]);
                    az[nt]  = MFMA16(Wzh, Hb[kt * 2 + nt], az[nt]);
                    ain[nt] = MFMA16(Wni, Ba[kt * 2 + nt], ain[nt]);
                    ahn[nt] = MFMA16(Wnh, Hb[kt * 2 + nt], ahn[nt]);
                }
            }
            __builtin_amdgcn_s_setprio(0);

            #pragma unroll
            for (int nt = 0; nt < 2; ++nt) {
                int node = nt * 16 + col;
                s16x4 h04 = hbl[gd * 2 + nt];
                f32x4 out;
                #pragma unroll
                for (int r = 0; r < 4; ++r) {
                    float rg = sigm(ar[nt][r] + br[r]);
                    float zg = sigm(az[nt][r] + bz[r]);
                    float e2 = __expf(2.f * (ain[nt][r] + bin[r] + rg * (ahn[nt][r] + bhn[r])));
                    float ng = 1.f - 2.f / (e2 + 1.f);
                    out[r] = (1.f - zg) * ng + zg * bf2f((unsigned short)h04[r]);
                }
                *(f32x4*)(eb + node * 256 + ((db * 4) ^ ((node & 7) << 4))) = out;
            }
        }

        // coalesced flush + fused value head
        {
            float* ho = hid + (size_t)env * 2048;
            float vsum = 0.f;
            #pragma unroll
            for (int i = 0; i < 8; ++i) {
                int idx4 = l + i * 64;
                int node = idx4 >> 4, q = idx4 & 15;
                f32x4 hv = *(const f32x4*)(eb + node * 256 + ((q * 16) ^ ((node & 7) << 4)));
                ((f32x4*)ho)[idx4] = hv;
                f32x4 wv = ((const f32x4*)W_out)[idx4];
                vsum += hv[0] * wv[0] + hv[1] * wv[1] + hv[2] * wv[2] + hv[3] * wv[3];
            }
            #pragma unroll
            for (int off = 32; off > 0; off >>= 1) vsum += __shfl_down(vsum, off, 64);
            if (l == 0) value[env] = vsum + b_out[0];
        }
    };

    computeEnv(0);
    __syncthreads();                 // all waves done reading their eb (group0)

    // ---- write group1 regs -> LDS (cooperative, crosses wave regions) ----
    {
        #pragma unroll
        for (int i = 0; i < 4; ++i) {
            int idx = t + i * 256, e = idx >> 8, q = idx & 255;
            *(s16x8*)(smem + 49152 + e * 8192 + q * 16) = aggv[i];
        }
        #pragma unroll
        for (int i = 0; i < 8; ++i) {
            int idx = t + i * 256;
            f32x4 hv = h0v[i];
            s16x4 pk;
            pk[0] = (short)f2bf(hv[0]); pk[1] = (short)f2bf(hv[1]);
            pk[2] = (short)f2bf(hv[2]); pk[3] = (short)f2bf(hv[3]);
            int e = idx >> 9, off = (idx & 511) * 8;
            int row = off >> 7, rb = off & 127;
            *(s16x4*)(smem + 49152 + e * 8192 + 4096 + row * 128 +
                      (rb ^ ((row & 7) << 4))) = pk;
        }
    }
    __syncthreads();

    computeEnv(1);
}

// ---------------------------------------------------------------------------------
extern "C" void kernel_launch(void* const* d_in, const int* in_sizes, int n_in,
                              void* d_out, int out_size, void* d_ws, size_t ws_size,
                              hipStream_t stream)
{
    const float* x     = (const float*)d_in[0];
    const void*  edge  = d_in[1];
    const float* h0    = (const float*)d_in[2];
    const float* W_pre = (const float*)d_in[3];
    const float* b_pre = (const float*)d_in[4];
    const float* W_gcn = (const float*)d_in[5];
    const float* b_gcn = (const float*)d_in[6];
    const float* W_ih  = (const float*)d_in[7];
    const float* W_hh  = (const float*)d_in[8];
    const float* b_ih  = (const float*)d_in[9];
    const float* b_hh  = (const float*)d_in[10];
    const float* W_out = (const float*)d_in[11];
    const float* b_out = (const float*)d_in[12];

    float* value = (float*)d_out;
    float* hid   = (float*)d_out + NENV;

    short* WcTB = (short*)d_ws;                          // 2048 bf16
    float* bcw  = (float*)((char*)d_ws + 4096);          // 64 f32
    short* WihB = (short*)((char*)d_ws + 4608);          // 12288 bf16
    short* WhhB = WihB + RD3 * GD;                       // 12288 bf16

    prep_kernel<<<97, 256, 0, stream>>>(W_pre, b_pre, W_gcn, W_ih, W_hh,
                                        WcTB, bcw, WihB, WhhB);
    gcn_kernel<<<512, 256, 0, stream>>>(x, edge, bcw, b_gcn, WcTB, hid);
    gru_kernel<<<512, 256, 0, stream>>>(h0, WihB, WhhB, b_ih, b_hh,
                                        W_out, b_out, value, hid);
}

// Round 12
// 64.092 us; speedup vs baseline: 1.0835x; 1.0835x over previous
//
#include <hip/hip_runtime.h>

constexpr int NENV = 4096;
constexpr int GD   = 64;

typedef __attribute__((ext_vector_type(8))) short s16x8;
typedef __attribute__((ext_vector_type(4))) short s16x4;
typedef __attribute__((ext_vector_type(4))) float f32x4;

__device__ __forceinline__ unsigned short f2bf(float f) {
    unsigned u = __float_as_uint(f);
    u += 0x7FFFu + ((u >> 16) & 1u);
    return (unsigned short)(u >> 16);
}
__device__ __forceinline__ float bf2f(unsigned short u) {
    return __uint_as_float((unsigned)u << 16);
}
__device__ __forceinline__ float sigm(float v) { return 1.f / (1.f + __expf(-v)); }

__device__ __forceinline__ s16x8 cvt8(const float* p) {
    f32x4 a = *(const f32x4*)p;
    f32x4 b = *(const f32x4*)(p + 4);
    s16x8 r;
    r[0] = (short)f2bf(a[0]); r[1] = (short)f2bf(a[1]);
    r[2] = (short)f2bf(a[2]); r[3] = (short)f2bf(a[3]);
    r[4] = (short)f2bf(b[0]); r[5] = (short)f2bf(b[1]);
    r[6] = (short)f2bf(b[2]); r[7] = (short)f2bf(b[3]);
    return r;
}

#define MFMA16(A, B, C) __builtin_amdgcn_mfma_f32_16x16x32_bf16(A, B, C, 0, 0, 0)

// ==== SINGLE fused kernel: inline prep + wave-per-env GCN + cooperative GRU. ====
// 1024 blocks x 256 thr, 4 envs/block, 3 barriers, 77KB LDS (2 blocks/CU).
// Per-env region (stride 17920B): cnts f32[32][36]@0 (-> yB; -> hnew f32 s68),
//   xT bf16[32][40]@4608, Ah bf16[32][40]@7168, aggB swz@9728, h0B swz@13824.
// Shared: dinv@71680, rsum@72192, WcT bf16[64][32]@72704, bcw f32[64]@76800.
__global__ __launch_bounds__(256) void fused_kernel(
    const float* __restrict__ x,      // [4096][32][32]
    const void*  __restrict__ edge,   // [4096][2][256] int32 or int64
    const float* __restrict__ h0f,    // [N][64]
    const float* __restrict__ W_pre,  // [32][64]
    const float* __restrict__ b_pre,  // [64]
    const float* __restrict__ W_gcn,  // [64][64]
    const float* __restrict__ b_gcn,  // [64]
    const float* __restrict__ W_ih,   // [192][64]
    const float* __restrict__ W_hh,   // [192][64]
    const float* __restrict__ b_ih, const float* __restrict__ b_hh,
    const float* __restrict__ W_out,  // [2048]
    const float* __restrict__ b_out,
    float* __restrict__ value,        // [4096]
    float* __restrict__ hid_out)      // [N][64]
{
    __shared__ __align__(16) char smem[77056];

    const int t   = threadIdx.x;
    const int w   = t >> 6;
    const int l   = t & 63;
    const int col = l & 15, lg = l >> 4;
    const int env = blockIdx.x * 4 + w;

    char*  eb    = smem + w * 17920;
    float* cnts  = (float*)eb;
    short* yB    = (short*)eb;
    short* xT    = (short*)(eb + 4608);
    short* Ah    = (short*)(eb + 7168);
    float* sdinv = (float*)(smem + 71680) + w * 32;
    float* srsum = (float*)(smem + 72192) + w * 32;
    short* wct   = (short*)(smem + 72704);
    float* bcw_s = (float*)(smem + 76800);

    // ================= P0: issue global loads =================
    const int4* pg = (const int4*)edge;   // dtype probe (first 2KB)
    int4 pa = pg[l], pb = pg[l + 64];
    f32x4 xq[4], hq[8];
    #pragma unroll
    for (int i = 0; i < 4; ++i) xq[i] = ((const f32x4*)(x + (size_t)env * 1024))[l + i * 64];
    #pragma unroll
    for (int i = 0; i < 8; ++i) hq[i] = ((const f32x4*)(h0f + (size_t)env * 2048))[l + i * 64];

    const bool is32 = (__any((pa.y | pa.w | pb.y | pb.w) != 0) != 0);
    int rr_[4], cc_[4];
    if (is32) {
        const int4* e4 = (const int4*)((const char*)edge + (size_t)env * 2048);
        int4 r4 = e4[l], c4 = e4[64 + l];
        rr_[0] = r4.x; rr_[1] = r4.y; rr_[2] = r4.z; rr_[3] = r4.w;
        cc_[0] = c4.x; cc_[1] = c4.y; cc_[2] = c4.z; cc_[3] = c4.w;
    } else {
        const int4* e4 = (const int4*)((const char*)edge + (size_t)env * 4096);
        int4 ra = e4[2 * l], rb = e4[2 * l + 1];
        int4 ca = e4[128 + 2 * l], cb = e4[128 + 2 * l + 1];
        rr_[0] = ra.x; rr_[1] = ra.z; rr_[2] = rb.x; rr_[3] = rb.z;
        cc_[0] = ca.x; cc_[1] = ca.z; cc_[2] = cb.x; cc_[3] = cb.z;
    }

    // ================= Pprep (wave-specialized): WcT via MFMA, bcw scalar ========
    if (w == 0) {
        // A = W_gcn^T fragments (row d = a*16+col, elems m = k2*32+lg*8+j)
        s16x8 Af[4][2];
        #pragma unroll
        for (int a = 0; a < 4; ++a)
            #pragma unroll
            for (int k2 = 0; k2 < 2; ++k2) {
                s16x8 f;
                #pragma unroll
                for (int j = 0; j < 8; ++j) {
                    int m = k2 * 32 + lg * 8 + j;
                    f[j] = (short)f2bf(W_gcn[m * 64 + a * 16 + col]);
                }
                Af[a][k2] = f;
            }
        // B = W_pre^T fragments (col kin = kc*16+col, elems m contiguous)
        s16x8 Bf[2][2];
        #pragma unroll
        for (int kc = 0; kc < 2; ++kc)
            #pragma unroll
            for (int k2 = 0; k2 < 2; ++k2)
                Bf[kc][k2] = cvt8(W_pre + (kc * 16 + col) * 64 + k2 * 32 + lg * 8);
        #pragma unroll
        for (int a = 0; a < 4; ++a)
            #pragma unroll
            for (int kc = 0; kc < 2; ++kc) {
                f32x4 d4 = {};
                d4 = MFMA16(Af[a][0], Bf[kc][0], d4);
                d4 = MFMA16(Af[a][1], Bf[kc][1], d4);
                #pragma unroll
                for (int r = 0; r < 4; ++r)
                    wct[(a * 16 + lg * 4 + r) * 32 + kc * 16 + col] = (short)f2bf(d4[r]);
            }
    } else if (w == 1) {
        float acc = 0.f;
        for (int m = 0; m < 64; ++m) acc += b_pre[m] * W_gcn[m * 64 + l];
        bcw_s[l] = acc;
    }

    // ================= P1: zero counts, stage xT / h0B (wave-local) ==============
    #pragma unroll
    for (int i = 0; i < 5; ++i) {
        int o = l + i * 64;
        if (o < 288) ((f32x4*)cnts)[o] = (f32x4){0.f, 0.f, 0.f, 0.f};
    }
    #pragma unroll
    for (int i = 0; i < 4; ++i) {         // x -> xT bf16 (feature-major)
        int idx4 = l + i * 64;
        int n = idx4 >> 3, q = idx4 & 7;
        #pragma unroll
        for (int j = 0; j < 4; ++j) xT[(q * 4 + j) * 40 + n] = (short)f2bf(xq[i][j]);
    }
    char* h0b = eb + 13824;
    #pragma unroll
    for (int i = 0; i < 8; ++i) {         // h0 -> swizzled bf16 rows (128B)
        int idx4 = l + i * 64;
        int n = idx4 >> 4, q = idx4 & 15;
        s16x4 pk;
        pk[0] = (short)f2bf(hq[i][0]); pk[1] = (short)f2bf(hq[i][1]);
        pk[2] = (short)f2bf(hq[i][2]); pk[3] = (short)f2bf(hq[i][3]);
        *(s16x4*)(h0b + n * 128 + ((q * 8) ^ ((n & 7) << 4))) = pk;
    }

    // ================= P2: adjacency counts (wave-local atomics) =================
    #pragma unroll
    for (int j = 0; j < 4; ++j) atomicAdd(cnts + cc_[j] * 36 + rr_[j], 1.0f);

    // ================= P3: degree + dinv (2 lanes per target row) ================
    const int c_  = l >> 1;
    const int r0_ = (l & 1) * 16;
    f32x4 cv[4];
    float s16s = 0.f;
    #pragma unroll
    for (int q = 0; q < 4; ++q) {
        cv[q] = *(const f32x4*)(cnts + c_ * 36 + r0_ + q * 4);
        s16s += cv[q][0] + cv[q][1] + cv[q][2] + cv[q][3];
    }
    float degs = s16s + __shfl_xor(s16s, 1, 64);
    float dc = rsqrtf(1.0f + degs);
    if (!(l & 1)) sdinv[c_] = dc;

    // ================= P4: normalize -> Ah bf16, rowsum ==========================
    {
        f32x4 dv[4];
        #pragma unroll
        for (int q = 0; q < 4; ++q) dv[q] = *(const f32x4*)(sdinv + r0_ + q * 4);
        float dot = 0.f;
        s16x8 o0, o1;
        #pragma unroll
        for (int k = 0; k < 16; ++k) {
            float u = cv[k >> 2][k & 3] * dv[k >> 2][k & 3];
            dot += u;
            float v = u * dc;
            if (r0_ + k == c_) v += dc * dc;
            if (k < 8) o0[k] = (short)f2bf(v); else o1[k - 8] = (short)f2bf(v);
        }
        dot += __shfl_xor(dot, 1, 64);
        if (!(l & 1)) srsum[c_] = dc * dot + dc * dc;
        *(s16x8*)(Ah + c_ * 40 + r0_)     = o0;
        *(s16x8*)(Ah + c_ * 40 + r0_ + 8) = o1;
    }

    // ================= P5: yT = xT @ AhatT (4 MFMA) -> yB[node][feat] ============
    {
        s16x8 Ax0 = *(const s16x8*)(xT + col * 40 + lg * 8);
        s16x8 Ax1 = *(const s16x8*)(xT + (16 + col) * 40 + lg * 8);
        s16x8 Af0 = *(const s16x8*)(Ah + col * 40 + lg * 8);
        s16x8 Af1 = *(const s16x8*)(Ah + (16 + col) * 40 + lg * 8);
        f32x4 y00 = {}, y01 = {}, y10 = {}, y11 = {};
        y00 = MFMA16(Ax0, Af0, y00);
        y01 = MFMA16(Ax0, Af1, y01);
        y10 = MFMA16(Ax1, Af0, y10);
        y11 = MFMA16(Ax1, Af1, y11);
        #pragma unroll
        for (int f = 0; f < 2; ++f)
            #pragma unroll
            for (int d = 0; d < 2; ++d) {
                f32x4 a = (f == 0) ? (d == 0 ? y00 : y01) : (d == 0 ? y10 : y11);
                s16x4 pk;
                pk[0] = (short)f2bf(a[0]); pk[1] = (short)f2bf(a[1]);
                pk[2] = (short)f2bf(a[2]); pk[3] = (short)f2bf(a[3]);
                *(s16x4*)(yB + (d * 16 + col) * 40 + f * 16 + lg * 4) = pk;
            }
    }

    __syncthreads();   // ---- barrier A: WcT/bcw ready (prep consumers ahead) ----

    // ================= P6: aggT = WcT @ yT (8 MFMA) -> aggB swz ==================
    {
        s16x8 Aw[4];
        #pragma unroll
        for (int a = 0; a < 4; ++a)
            Aw[a] = *(const s16x8*)(wct + (a * 16 + col) * 32 + lg * 8);
        s16x8 By0 = *(const s16x8*)(yB + col * 40 + lg * 8);
        s16x8 By1 = *(const s16x8*)(yB + (16 + col) * 40 + lg * 8);
        float rs0 = srsum[col], rs1 = srsum[16 + col];
        char* ab = eb + 9728;
        #pragma unroll
        for (int a = 0; a < 4; ++a) {
            f32x4 g0 = {}, g1 = {};
            g0 = MFMA16(Aw[a], By0, g0);
            g1 = MFMA16(Aw[a], By1, g1);
            f32x4 bc4 = *(const f32x4*)(bcw_s + a * 16 + lg * 4);
            f32x4 bg4 = *(const f32x4*)(b_gcn + a * 16 + lg * 4);
            #pragma unroll
            for (int n = 0; n < 2; ++n) {
                f32x4 g = n ? g1 : g0;
                float rs = n ? rs1 : rs0;
                int node = n * 16 + col;
                s16x4 pk;
                #pragma unroll
                for (int r = 0; r < 4; ++r) pk[r] = (short)f2bf(g[r] + rs * bc4[r] + bg4[r]);
                *(s16x4*)(ab + node * 128 + ((a * 32 + lg * 8) ^ ((node & 7) << 4))) = pk;
            }
        }
    }
    __syncthreads();   // ---- barrier B: all envs' aggB/h0B ready ----

    // ================= P7: GRU — wave w owns d-slice [16w,16w+16) ================
    f32x4 accr[8] = {}, accz[8] = {}, accin[8] = {}, acchn[8] = {};
    #pragma unroll
    for (int kt = 0; kt < 2; ++kt) {
        const int wr = (16 * w + col) * 64 + kt * 32 + lg * 8;
        s16x8 Ari = cvt8(W_ih + wr);
        s16x8 Azi = cvt8(W_ih + 64 * 64 + wr);
        s16x8 Ani = cvt8(W_ih + 128 * 64 + wr);
        s16x8 Arh = cvt8(W_hh + wr);
        s16x8 Azh = cvt8(W_hh + 64 * 64 + wr);
        s16x8 Anh = cvt8(W_hh + 128 * 64 + wr);
        #pragma unroll
        for (int nt = 0; nt < 8; ++nt) {
            char* ab = smem + (nt >> 1) * 17920 + 9728;
            char* hb = smem + (nt >> 1) * 17920 + 13824;
            int node = (nt & 1) * 16 + col;
            int off = node * 128 + ((kt * 64 + lg * 16) ^ ((node & 7) << 4));
            s16x8 Ba = *(const s16x8*)(ab + off);
            s16x8 Bh = *(const s16x8*)(hb + off);
            accr[nt]  = MFMA16(Ari, Ba, accr[nt]);
            accr[nt]  = MFMA16(Arh, Bh, accr[nt]);
            accz[nt]  = MFMA16(Azi, Ba, accz[nt]);
            accz[nt]  = MFMA16(Azh, Bh, accz[nt]);
            accin[nt] = MFMA16(Ani, Ba, accin[nt]);
            acchn[nt] = MFMA16(Anh, Bh, acchn[nt]);
        }
    }
    {
        const int db = 16 * w + lg * 4;
        f32x4 br  = *(const f32x4*)(b_ih + db);
        f32x4 bz  = *(const f32x4*)(b_ih + 64 + db);
        f32x4 bin = *(const f32x4*)(b_ih + 128 + db);
        f32x4 bhn = *(const f32x4*)(b_hh + 128 + db);
        {
            f32x4 t1 = *(const f32x4*)(b_hh + db);
            f32x4 t2 = *(const f32x4*)(b_hh + 64 + db);
            br += t1; bz += t2;
        }
        #pragma unroll
        for (int nt = 0; nt < 8; ++nt) {
            char* hb = smem + (nt >> 1) * 17920 + 13824;
            float* hnew = (float*)(smem + (nt >> 1) * 17920);
            int node = (nt & 1) * 16 + col;
            s16x4 h04 = *(const s16x4*)(hb + node * 128 + ((32 * w + 8 * lg) ^ ((node & 7) << 4)));
            f32x4 out;
            #pragma unroll
            for (int r = 0; r < 4; ++r) {
                float rg = sigm(accr[nt][r] + br[r]);
                float zg = sigm(accz[nt][r] + bz[r]);
                float e2 = __expf(2.f * (accin[nt][r] + bin[r] + rg * (acchn[nt][r] + bhn[r])));
                float ng = 1.f - 2.f / (e2 + 1.f);
                out[r] = (1.f - zg) * ng + zg * bf2f((unsigned short)h04[r]);
            }
            *(f32x4*)(hnew + node * 68 + db) = out;
        }
    }
    __syncthreads();   // ---- barrier C: hnew complete ----

    // ================= P8: flush + value head (wave w -> env w) ===================
    {
        float* hn = (float*)(smem + w * 17920);
        float* ho = hid_out + (size_t)env * 2048;
        float vsum = 0.f;
        #pragma unroll
        for (int i = 0; i < 8; ++i) {
            int idx4 = l + i * 64;
            int row = idx4 >> 4, q = idx4 & 15;
            f32x4 hv = *(const f32x4*)(hn + row * 68 + q * 4);
            ((f32x4*)ho)[idx4] = hv;
            f32x4 wv = ((const f32x4*)W_out)[idx4];
            vsum += hv[0] * wv[0] + hv[1] * wv[1] + hv[2] * wv[2] + hv[3] * wv[3];
        }
        #pragma unroll
        for (int off = 32; off > 0; off >>= 1) vsum += __shfl_down(vsum, off, 64);
        if (l == 0) value[env] = vsum + b_out[0];
    }
}

// ---------------------------------------------------------------------------------
extern "C" void kernel_launch(void* const* d_in, const int* in_sizes, int n_in,
                              void* d_out, int out_size, void* d_ws, size_t ws_size,
                              hipStream_t stream)
{
    const float* x     = (const float*)d_in[0];
    const void*  edge  = d_in[1];
    const float* h0    = (const float*)d_in[2];
    const float* W_pre = (const float*)d_in[3];
    const float* b_pre = (const float*)d_in[4];
    const float* W_gcn = (const float*)d_in[5];
    const float* b_gcn = (const float*)d_in[6];
    const float* W_ih  = (const float*)d_in[7];
    const float* W_hh  = (const float*)d_in[8];
    const float* b_ih  = (const float*)d_in[9];
    const float* b_hh  = (const float*)d_in[10];
    const float* W_out = (const float*)d_in[11];
    const float* b_out = (const float*)d_in[12];

    float* value = (float*)d_out;
    float* hid   = (float*)d_out + NENV;

    fused_kernel<<<NENV / 4, 256, 0, stream>>>(x, edge, h0, W_pre, b_pre, W_gcn,
                                               b_gcn, W_ih, W_hh, b_ih, b_hh,
                                               W_out, b_out, value, hid);
}